// Round 23
// baseline (18.285 us; speedup 1.0000x reference)
//
#include <hip/hip_runtime.h>
#include <hip/hip_fp16.h>

// GSplat renderer as a bf16 MFMA GEMM — R23 = R22 (16.82us) with KSPLIT 8->4:
// each block processes 512 gaussians (4 staged chunks of 128), partials
// [4][1024][256] fp16 = 2 MB (was 4), finalize reads 2 MB. Work per CU
// invariant; grid (16,4,4) = 256 blocks = 1/CU (R18~R21 showed cross-block
// overlap ~0, so this should be pure traffic savings).

constexpr int PIX = 65536;
constexpr int KB = 512;      // gaussians per block (4 chunks of 128)
constexpr int KCH = 128;     // per staging chunk
constexpr int NCHUNKS = 4;
constexpr int KSPLIT = 4;
constexpr int MT = 64;
constexpr int NT = 64;
constexpr float COORD_STEP = 2.0f / 255.0f;

typedef __attribute__((ext_vector_type(8))) short short8;
typedef __attribute__((ext_vector_type(4))) float f32x4;

__device__ __forceinline__ unsigned cvt_pk_bf16(float lo, float hi) {
  unsigned r;
  asm("v_cvt_pk_bf16_f32 %0, %1, %2" : "=v"(r) : "v"(lo), "v"(hi));
  return r;
}

__global__ __launch_bounds__(256) void gs_mfma(
    const float* __restrict__ means, const float* __restrict__ scales,
    const float* __restrict__ opac, const float* __restrict__ colors,
    __half* __restrict__ partials) {
  __shared__ unsigned short A_l[MT * KCH];  // bf16 bits, swizzled (16 KB)
  __shared__ unsigned short B_l[NT * KCH];  // bf16 bits, swizzled (16 KB)
  __shared__ float pxL[KB], pyL[KB], kKL[KB], colL[KB];  // 8 KB

  const int t = threadIdx.x;
  const int mt = blockIdx.x;          // 0..15: c = mt>>2, rowband (mt&3)*64
  const int nt = blockIdx.y;          // 0..3
  const int kp = blockIdx.z;          // 0..3
  const int c = mt >> 2;
  const int row0 = (mt & 3) * MT;
  const int col0 = nt * NT;

  // --- params for all 4 chunks (2 gaussians per thread) ---
#pragma unroll
  for (int h = 0; h < 2; ++h) {
    int loc = t + h * 256;
    int n = kp * KB + loc;
    float mx = means[3 * n], my = means[3 * n + 1], mz = means[3 * n + 2];
    float scl = fmaxf((scales[3 * n] + scales[3 * n + 1] + scales[3 * n + 2]) * (1.0f / 3.0f), 1e-4f);
    float op = opac[n];
    float rzs = 1.0f / (fabsf(mz) + 1.0f);
    float sigma = fminf(fmaxf(scl * rzs, 0.02f), 0.5f);
    float inv_s = 1.0f / sigma;
    pxL[loc] = tanhf(mx * rzs);
    pyL[loc] = tanhf(my * rzs);
    kKL[loc] = -0.72134752044f * inv_s * inv_s;  // -0.5/ln2 * inv_s^2
    colL[loc] = (c < 3) ? op * colors[3 * n + c] : op;
  }

  // MFMA lane mapping (constant across chunks)
  const int w = t >> 6;
  const int lr = t & 15;
  const int lg = (t >> 4) & 3;
  const int ra = w * 16 + lr;
  const unsigned offA = (unsigned)(ra * 256 + lg * 16);
  const unsigned swA = (unsigned)((ra & 7) << 4);
  const unsigned swB = (unsigned)((lr & 7) << 4);
  const unsigned offB0 = (unsigned)((0 * 16 + lr) * 256 + lg * 16);
  const unsigned offB1 = (unsigned)((1 * 16 + lr) * 256 + lg * 16);
  const unsigned offB2 = (unsigned)((2 * 16 + lr) * 256 + lg * 16);
  const unsigned offB3 = (unsigned)((3 * 16 + lr) * 256 + lg * 16);

  f32x4 acc0 = {0.f, 0.f, 0.f, 0.f};
  f32x4 acc1 = acc0, acc2 = acc0, acc3 = acc0;

  // staging thread mapping
  const int kq = (t & 31) << 2;       // 4 gaussians (local k)
  const int mq = (t >> 5) << 3;       // 8 rows/cols
  const int kbyte = (t & 31) << 3;

  for (int cc = 0; cc < NCHUNKS; ++cc) {
    __syncthreads();   // params ready (cc=0) / prior MFMA reads done (cc>0)

    // --- stage A (ey*col) and Bt (ex), bf16, swizzled ---
    {
      const int kk = cc * KCH + kq;
      float py0 = pyL[kk + 0], py1 = pyL[kk + 1], py2 = pyL[kk + 2], py3 = pyL[kk + 3];
      float px0 = pxL[kk + 0], px1 = pxL[kk + 1], px2 = pxL[kk + 2], px3 = pxL[kk + 3];
      float K0 = kKL[kk + 0], K1 = kKL[kk + 1], K2 = kKL[kk + 2], K3 = kKL[kk + 3];
      float c0 = colL[kk + 0], c1 = colL[kk + 1], c2 = colL[kk + 2], c3 = colL[kk + 3];
#pragma unroll 4
      for (int j = 0; j < 8; ++j) {
        int m = mq + j;
        float cr = -1.0f + COORD_STEP * (float)(row0 + m);
        float d0 = cr - py0, d1 = cr - py1, d2 = cr - py2, d3 = cr - py3;
        float e0 = exp2f(K0 * d0 * d0) * c0;
        float e1 = exp2f(K1 * d1 * d1) * c1;
        float e2 = exp2f(K2 * d2 * d2) * c2;
        float e3 = exp2f(K3 * d3 * d3) * c3;
        uint2 pa;
        pa.x = cvt_pk_bf16(e0, e1);
        pa.y = cvt_pk_bf16(e2, e3);
        *(uint2*)((char*)A_l + ((m * 256 + kbyte) ^ ((m & 7) << 4))) = pa;
        float ccoord = -1.0f + COORD_STEP * (float)(col0 + m);
        float f0 = ccoord - px0, f1 = ccoord - px1, f2 = ccoord - px2, f3 = ccoord - px3;
        float g0 = exp2f(K0 * f0 * f0);
        float g1 = exp2f(K1 * f1 * f1);
        float g2 = exp2f(K2 * f2 * f2);
        float g3 = exp2f(K3 * f3 * f3);
        uint2 pb;
        pb.x = cvt_pk_bf16(g0, g1);
        pb.y = cvt_pk_bf16(g2, g3);
        *(uint2*)((char*)B_l + ((m * 256 + kbyte) ^ ((m & 7) << 4))) = pb;
      }
    }
    __syncthreads();

    // --- MFMA: 4 s-steps per chunk ---
#pragma unroll
    for (int s = 0; s < 4; ++s) {
      const unsigned ks = (unsigned)(s * 64);
      short8 af = *(const short8*)((const char*)A_l + ((offA + ks) ^ swA));
      short8 b0 = *(const short8*)((const char*)B_l + ((offB0 + ks) ^ swB));
      short8 b1 = *(const short8*)((const char*)B_l + ((offB1 + ks) ^ swB));
      short8 b2 = *(const short8*)((const char*)B_l + ((offB2 + ks) ^ swB));
      short8 b3 = *(const short8*)((const char*)B_l + ((offB3 + ks) ^ swB));
      acc0 = __builtin_amdgcn_mfma_f32_16x16x32_bf16(af, b0, acc0, 0, 0, 0);
      acc1 = __builtin_amdgcn_mfma_f32_16x16x32_bf16(af, b1, acc1, 0, 0, 0);
      acc2 = __builtin_amdgcn_mfma_f32_16x16x32_bf16(af, b2, acc2, 0, 0, 0);
      acc3 = __builtin_amdgcn_mfma_f32_16x16x32_bf16(af, b3, acc3, 0, 0, 0);
    }
  }

  // --- epilogue: fp16 partials; D col=lane&15, row=lg*4+r (m89/m91) ---
  {
    __half* pb = partials +
        (((size_t)kp * 1024 + c * 256 + row0 + w * 16 + lg * 4) * 256) +
        col0 + lr;
#pragma unroll
    for (int r = 0; r < 4; ++r) {
      pb[r * 256 + 0]  = __float2half(acc0[r]);
      pb[r * 256 + 16] = __float2half(acc1[r]);
      pb[r * 256 + 32] = __float2half(acc2[r]);
      pb[r * 256 + 48] = __float2half(acc3[r]);
    }
  }
}

// grid = 256 blocks; thread = one pixel.
__global__ __launch_bounds__(256) void gs_finalize(
    const __half* __restrict__ partials, float* __restrict__ out) {
  int px = blockIdx.x * 256 + threadIdx.x;
  int row = px >> 8, col = px & 255;
  float s0 = 0.f, s1 = 0.f, s2 = 0.f, s3 = 0.f;
#pragma unroll
  for (int kp = 0; kp < KSPLIT; ++kp) {
    const __half* base = partials + (((size_t)kp * 4) * 256 + row) * 256 + col;
    s0 += __half2float(base[0 * 65536]);
    s1 += __half2float(base[1 * 65536]);
    s2 += __half2float(base[2 * 65536]);
    s3 += __half2float(base[3 * 65536]);
  }
  float inv = 1.0f / fmaxf(s3, 1e-5f);
  out[0 * PIX + px] = fminf(fmaxf(s0 * inv, 0.0f), 1.0f);
  out[1 * PIX + px] = fminf(fmaxf(s1 * inv, 0.0f), 1.0f);
  out[2 * PIX + px] = fminf(fmaxf(s2 * inv, 0.0f), 1.0f);
}

extern "C" void kernel_launch(void* const* d_in, const int* in_sizes, int n_in,
                              void* d_out, int out_size, void* d_ws, size_t ws_size,
                              hipStream_t stream) {
  const float* means = (const float*)d_in[0];
  // d_in[1] = quats (unused by reference)
  const float* scales = (const float*)d_in[2];
  const float* opac = (const float*)d_in[3];
  const float* colors = (const float*)d_in[4];
  float* out = (float*)d_out;

  // ws: partials [KSPLIT][1024][256] fp16 = 2 MB
  __half* partials = (__half*)d_ws;

  gs_mfma<<<dim3(16, 4, KSPLIT), 256, 0, stream>>>(
      means, scales, opac, colors, partials);
  gs_finalize<<<256, 256, 0, stream>>>(partials, out);
}

// Round 24
// 15.218 us; speedup vs baseline: 1.2016x; 1.2016x over previous
//
#include <hip/hip_runtime.h>
#include <hip/hip_fp16.h>

// GSplat renderer as a bf16 MFMA GEMM — R24 = R22 (best, 16.82us) with ONE
// change: exp2f() -> __builtin_amdgcn_exp2f (raw v_exp_f32). HIP's exp2f
// lowers to OCML with range/denorm fixup (~4-6 insts); our args are always
// <=0 so HW semantics (underflow->0) are exactly right. Staging is ~50% exp2
// by volume -> expect ~3x staging-cost cut.
// R23 lesson: 1 block/CU regressed; keep KSPLIT=8 (2 blocks/CU).
// GEMM: M=1024 (4c x 256 rows), N=256, K=2048; KCH=128 x 2 chunks/block;
// grid (16,4,8) = 512 blocks; LDS 36 KB; fp16 partials (4 MB).

constexpr int PIX = 65536;
constexpr int KB = 256;      // gaussians per block (2 chunks of 128)
constexpr int KCH = 128;     // per staging chunk
constexpr int KSPLIT = 8;
constexpr int MT = 64;
constexpr int NT = 64;
constexpr float COORD_STEP = 2.0f / 255.0f;

typedef __attribute__((ext_vector_type(8))) short short8;
typedef __attribute__((ext_vector_type(4))) float f32x4;

__device__ __forceinline__ unsigned cvt_pk_bf16(float lo, float hi) {
  unsigned r;
  asm("v_cvt_pk_bf16_f32 %0, %1, %2" : "=v"(r) : "v"(lo), "v"(hi));
  return r;
}
__device__ __forceinline__ float ex2(float x) {
  return __builtin_amdgcn_exp2f(x);   // bare v_exp_f32; args <= 0 here
}

__global__ __launch_bounds__(256) void gs_mfma(
    const float* __restrict__ means, const float* __restrict__ scales,
    const float* __restrict__ opac, const float* __restrict__ colors,
    __half* __restrict__ partials) {
  __shared__ unsigned short A_l[MT * KCH];  // bf16 bits, swizzled (16 KB)
  __shared__ unsigned short B_l[NT * KCH];  // bf16 bits, swizzled (16 KB)
  __shared__ float pxL[KB], pyL[KB], kKL[KB], colL[KB];  // 4 KB

  const int t = threadIdx.x;
  const int mt = blockIdx.x;          // 0..15: c = mt>>2, rowband (mt&3)*64
  const int nt = blockIdx.y;          // 0..3
  const int kp = blockIdx.z;          // 0..7
  const int c = mt >> 2;
  const int row0 = (mt & 3) * MT;
  const int col0 = nt * NT;

  // --- params for BOTH chunks (1 gaussian per thread, once) ---
  {
    int n = kp * KB + t;
    float mx = means[3 * n], my = means[3 * n + 1], mz = means[3 * n + 2];
    float scl = fmaxf((scales[3 * n] + scales[3 * n + 1] + scales[3 * n + 2]) * (1.0f / 3.0f), 1e-4f);
    float op = opac[n];
    float rzs = 1.0f / (fabsf(mz) + 1.0f);
    float sigma = fminf(fmaxf(scl * rzs, 0.02f), 0.5f);
    float inv_s = 1.0f / sigma;
    pxL[t] = tanhf(mx * rzs);
    pyL[t] = tanhf(my * rzs);
    kKL[t] = -0.72134752044f * inv_s * inv_s;  // -0.5/ln2 * inv_s^2
    colL[t] = (c < 3) ? op * colors[3 * n + c] : op;
  }

  // MFMA lane mapping (constant across chunks)
  const int w = t >> 6;
  const int lr = t & 15;
  const int lg = (t >> 4) & 3;
  const int ra = w * 16 + lr;
  const unsigned offA = (unsigned)(ra * 256 + lg * 16);
  const unsigned swA = (unsigned)((ra & 7) << 4);
  const unsigned swB = (unsigned)((lr & 7) << 4);
  const unsigned offB0 = (unsigned)((0 * 16 + lr) * 256 + lg * 16);
  const unsigned offB1 = (unsigned)((1 * 16 + lr) * 256 + lg * 16);
  const unsigned offB2 = (unsigned)((2 * 16 + lr) * 256 + lg * 16);
  const unsigned offB3 = (unsigned)((3 * 16 + lr) * 256 + lg * 16);

  f32x4 acc0 = {0.f, 0.f, 0.f, 0.f};
  f32x4 acc1 = acc0, acc2 = acc0, acc3 = acc0;

  // staging thread mapping
  const int kq = (t & 31) << 2;       // 4 gaussians (local k)
  const int mq = (t >> 5) << 3;       // 8 rows/cols
  const int kbyte = (t & 31) << 3;

  for (int cc = 0; cc < 2; ++cc) {
    __syncthreads();   // params ready (cc=0) / prior MFMA reads done (cc=1)

    // --- stage A (ey*col) and Bt (ex), bf16, swizzled ---
    {
      const int kk = cc * KCH + kq;
      float py0 = pyL[kk + 0], py1 = pyL[kk + 1], py2 = pyL[kk + 2], py3 = pyL[kk + 3];
      float px0 = pxL[kk + 0], px1 = pxL[kk + 1], px2 = pxL[kk + 2], px3 = pxL[kk + 3];
      float K0 = kKL[kk + 0], K1 = kKL[kk + 1], K2 = kKL[kk + 2], K3 = kKL[kk + 3];
      float c0 = colL[kk + 0], c1 = colL[kk + 1], c2 = colL[kk + 2], c3 = colL[kk + 3];
#pragma unroll 4
      for (int j = 0; j < 8; ++j) {
        int m = mq + j;
        float cr = -1.0f + COORD_STEP * (float)(row0 + m);
        float d0 = cr - py0, d1 = cr - py1, d2 = cr - py2, d3 = cr - py3;
        float e0 = ex2(K0 * d0 * d0) * c0;
        float e1 = ex2(K1 * d1 * d1) * c1;
        float e2 = ex2(K2 * d2 * d2) * c2;
        float e3 = ex2(K3 * d3 * d3) * c3;
        uint2 pa;
        pa.x = cvt_pk_bf16(e0, e1);
        pa.y = cvt_pk_bf16(e2, e3);
        *(uint2*)((char*)A_l + ((m * 256 + kbyte) ^ ((m & 7) << 4))) = pa;
        float ccoord = -1.0f + COORD_STEP * (float)(col0 + m);
        float f0 = ccoord - px0, f1 = ccoord - px1, f2 = ccoord - px2, f3 = ccoord - px3;
        float g0 = ex2(K0 * f0 * f0);
        float g1 = ex2(K1 * f1 * f1);
        float g2 = ex2(K2 * f2 * f2);
        float g3 = ex2(K3 * f3 * f3);
        uint2 pb;
        pb.x = cvt_pk_bf16(g0, g1);
        pb.y = cvt_pk_bf16(g2, g3);
        *(uint2*)((char*)B_l + ((m * 256 + kbyte) ^ ((m & 7) << 4))) = pb;
      }
    }
    __syncthreads();

    // --- MFMA: 4 s-steps per chunk ---
#pragma unroll
    for (int s = 0; s < 4; ++s) {
      const unsigned ks = (unsigned)(s * 64);
      short8 af = *(const short8*)((const char*)A_l + ((offA + ks) ^ swA));
      short8 b0 = *(const short8*)((const char*)B_l + ((offB0 + ks) ^ swB));
      short8 b1 = *(const short8*)((const char*)B_l + ((offB1 + ks) ^ swB));
      short8 b2 = *(const short8*)((const char*)B_l + ((offB2 + ks) ^ swB));
      short8 b3 = *(const short8*)((const char*)B_l + ((offB3 + ks) ^ swB));
      acc0 = __builtin_amdgcn_mfma_f32_16x16x32_bf16(af, b0, acc0, 0, 0, 0);
      acc1 = __builtin_amdgcn_mfma_f32_16x16x32_bf16(af, b1, acc1, 0, 0, 0);
      acc2 = __builtin_amdgcn_mfma_f32_16x16x32_bf16(af, b2, acc2, 0, 0, 0);
      acc3 = __builtin_amdgcn_mfma_f32_16x16x32_bf16(af, b3, acc3, 0, 0, 0);
    }
  }

  // --- epilogue: fp16 partials; D col=lane&15, row=lg*4+r (m89/m91) ---
  {
    __half* pb = partials +
        (((size_t)kp * 1024 + c * 256 + row0 + w * 16 + lg * 4) * 256) +
        col0 + lr;
#pragma unroll
    for (int r = 0; r < 4; ++r) {
      pb[r * 256 + 0]  = __float2half(acc0[r]);
      pb[r * 256 + 16] = __float2half(acc1[r]);
      pb[r * 256 + 32] = __float2half(acc2[r]);
      pb[r * 256 + 48] = __float2half(acc3[r]);
    }
  }
}

// grid = 256 blocks; thread = one pixel.
__global__ __launch_bounds__(256) void gs_finalize(
    const __half* __restrict__ partials, float* __restrict__ out) {
  int px = blockIdx.x * 256 + threadIdx.x;
  int row = px >> 8, col = px & 255;
  float s0 = 0.f, s1 = 0.f, s2 = 0.f, s3 = 0.f;
#pragma unroll
  for (int kp = 0; kp < KSPLIT; ++kp) {
    const __half* base = partials + (((size_t)kp * 4) * 256 + row) * 256 + col;
    s0 += __half2float(base[0 * 65536]);
    s1 += __half2float(base[1 * 65536]);
    s2 += __half2float(base[2 * 65536]);
    s3 += __half2float(base[3 * 65536]);
  }
  float inv = 1.0f / fmaxf(s3, 1e-5f);
  out[0 * PIX + px] = fminf(fmaxf(s0 * inv, 0.0f), 1.0f);
  out[1 * PIX + px] = fminf(fmaxf(s1 * inv, 0.0f), 1.0f);
  out[2 * PIX + px] = fminf(fmaxf(s2 * inv, 0.0f), 1.0f);
}

extern "C" void kernel_launch(void* const* d_in, const int* in_sizes, int n_in,
                              void* d_out, int out_size, void* d_ws, size_t ws_size,
                              hipStream_t stream) {
  const float* means = (const float*)d_in[0];
  // d_in[1] = quats (unused by reference)
  const float* scales = (const float*)d_in[2];
  const float* opac = (const float*)d_in[3];
  const float* colors = (const float*)d_in[4];
  float* out = (float*)d_out;

  // ws: partials [KSPLIT][1024][256] fp16 = 4 MB
  __half* partials = (__half*)d_ws;

  gs_mfma<<<dim3(16, 4, KSPLIT), 256, 0, stream>>>(
      means, scales, opac, colors, partials);
  gs_finalize<<<256, 256, 0, stream>>>(partials, out);
}

// Round 25
// 13.568 us; speedup vs baseline: 1.3477x; 1.1216x over previous
//
#include <hip/hip_runtime.h>
#include <hip/hip_fp16.h>

// GSplat renderer as a bf16 MFMA GEMM — R25 = R24 (15.22us) with staging math
// content halved, same layout/addresses:
//  (1) row-recurrence: w(d+s)=w(d)*r, r*=q (q=exp2(2Ks^2) precomputed/LDS);
//      exp2 per thread per chunk 64 -> 16. Underflow case analyzed safe
//      (w0=0 only when all true values < 2^-100 ~ 0 in bf16).
//  (2) manual tanh via exp2+rcp (~5 insts vs OCML ~25), rcp for divisions.
// Geometry: R22/R24 best — KSPLIT=8, KCH=128 x2 chunks, grid (16,4,8)=512
// blocks = 2/CU, LDS 36KB, fp16 partials (4MB).

constexpr int PIX = 65536;
constexpr int KB = 256;      // gaussians per block (2 chunks of 128)
constexpr int KCH = 128;     // per staging chunk
constexpr int KSPLIT = 8;
constexpr int MT = 64;
constexpr int NT = 64;
constexpr float COORD_STEP = 2.0f / 255.0f;
constexpr float TWO_S = 2.0f * COORD_STEP;
constexpr float S_SQ = COORD_STEP * COORD_STEP;

typedef __attribute__((ext_vector_type(8))) short short8;
typedef __attribute__((ext_vector_type(4))) float f32x4;

__device__ __forceinline__ unsigned cvt_pk_bf16(float lo, float hi) {
  unsigned r;
  asm("v_cvt_pk_bf16_f32 %0, %1, %2" : "=v"(r) : "v"(lo), "v"(hi));
  return r;
}
__device__ __forceinline__ float ex2(float x) {
  return __builtin_amdgcn_exp2f(x);   // bare v_exp_f32
}
__device__ __forceinline__ float rcp_(float x) {
  return __builtin_amdgcn_rcpf(x);    // v_rcp_f32, 1 ulp
}
__device__ __forceinline__ float tanh_fast(float x) {
  // tanh(x) = 1 - 2/(e^{2x}+1);  e^{2x} = exp2(2*log2e*x)
  float t = ex2(2.885390082f * x);
  return fmaf(-2.0f, rcp_(t + 1.0f), 1.0f);
}

__global__ __launch_bounds__(256) void gs_mfma(
    const float* __restrict__ means, const float* __restrict__ scales,
    const float* __restrict__ opac, const float* __restrict__ colors,
    __half* __restrict__ partials) {
  __shared__ unsigned short A_l[MT * KCH];  // bf16 bits, swizzled (16 KB)
  __shared__ unsigned short B_l[NT * KCH];  // bf16 bits, swizzled (16 KB)
  __shared__ float pxL[KB], pyL[KB], kKL[KB], colL[KB], qL[KB];  // 5 KB

  const int t = threadIdx.x;
  const int mt = blockIdx.x;          // 0..15: c = mt>>2, rowband (mt&3)*64
  const int nt = blockIdx.y;          // 0..3
  const int kp = blockIdx.z;          // 0..7
  const int c = mt >> 2;
  const int row0 = (mt & 3) * MT;
  const int col0 = nt * NT;

  // --- params for BOTH chunks (1 gaussian per thread, once) ---
  {
    int n = kp * KB + t;
    float mx = means[3 * n], my = means[3 * n + 1], mz = means[3 * n + 2];
    float scl = fmaxf((scales[3 * n] + scales[3 * n + 1] + scales[3 * n + 2]) * (1.0f / 3.0f), 1e-4f);
    float op = opac[n];
    float rzs = rcp_(fabsf(mz) + 1.0f);
    float sigma = fminf(fmaxf(scl * rzs, 0.02f), 0.5f);
    float inv_s = rcp_(sigma);
    float K = -0.72134752044f * inv_s * inv_s;  // -0.5/ln2 * inv_s^2
    pxL[t] = tanh_fast(mx * rzs);
    pyL[t] = tanh_fast(my * rzs);
    kKL[t] = K;
    qL[t] = ex2(2.0f * K * S_SQ);               // ratio-of-ratio
    colL[t] = (c < 3) ? op * colors[3 * n + c] : op;
  }

  // MFMA lane mapping (constant across chunks)
  const int w = t >> 6;
  const int lr = t & 15;
  const int lg = (t >> 4) & 3;
  const int ra = w * 16 + lr;
  const unsigned offA = (unsigned)(ra * 256 + lg * 16);
  const unsigned swA = (unsigned)((ra & 7) << 4);
  const unsigned swB = (unsigned)((lr & 7) << 4);
  const unsigned offB0 = (unsigned)((0 * 16 + lr) * 256 + lg * 16);
  const unsigned offB1 = (unsigned)((1 * 16 + lr) * 256 + lg * 16);
  const unsigned offB2 = (unsigned)((2 * 16 + lr) * 256 + lg * 16);
  const unsigned offB3 = (unsigned)((3 * 16 + lr) * 256 + lg * 16);

  f32x4 acc0 = {0.f, 0.f, 0.f, 0.f};
  f32x4 acc1 = acc0, acc2 = acc0, acc3 = acc0;

  // staging thread mapping
  const int kq = (t & 31) << 2;       // 4 gaussians (local k)
  const int mq = (t >> 5) << 3;       // 8 rows/cols
  const int kbyte = (t & 31) << 3;

  for (int cc = 0; cc < 2; ++cc) {
    __syncthreads();   // params ready (cc=0) / prior MFMA reads done (cc=1)

    // --- stage A (ey*col) and Bt (ex), bf16, swizzled, recurrence ---
    {
      const int kk = cc * KCH + kq;
      const float crA0 = -1.0f + COORD_STEP * (float)(row0 + mq);
      const float ccB0 = -1.0f + COORD_STEP * (float)(col0 + mq);
      float wA[4], rA[4], wB[4], rB[4], qv[4], cvv[4];
#pragma unroll
      for (int i = 0; i < 4; ++i) {
        float K = kKL[kk + i];
        float py = pyL[kk + i];
        float px = pxL[kk + i];
        qv[i] = qL[kk + i];
        cvv[i] = colL[kk + i];
        float dA = crA0 - py;
        wA[i] = ex2(K * dA * dA);
        rA[i] = ex2(K * fmaf(TWO_S, dA, S_SQ));
        float dB = ccB0 - px;
        wB[i] = ex2(K * dB * dB);
        rB[i] = ex2(K * fmaf(TWO_S, dB, S_SQ));
      }
#pragma unroll
      for (int j = 0; j < 8; ++j) {
        int m = mq + j;
        uint2 pa, pb;
        pa.x = cvt_pk_bf16(wA[0] * cvv[0], wA[1] * cvv[1]);
        pa.y = cvt_pk_bf16(wA[2] * cvv[2], wA[3] * cvv[3]);
        pb.x = cvt_pk_bf16(wB[0], wB[1]);
        pb.y = cvt_pk_bf16(wB[2], wB[3]);
        *(uint2*)((char*)A_l + ((m * 256 + kbyte) ^ ((m & 7) << 4))) = pa;
        *(uint2*)((char*)B_l + ((m * 256 + kbyte) ^ ((m & 7) << 4))) = pb;
#pragma unroll
        for (int i = 0; i < 4; ++i) {
          wA[i] *= rA[i]; rA[i] *= qv[i];
          wB[i] *= rB[i]; rB[i] *= qv[i];
        }
      }
    }
    __syncthreads();

    // --- MFMA: 4 s-steps per chunk ---
#pragma unroll
    for (int s = 0; s < 4; ++s) {
      const unsigned ks = (unsigned)(s * 64);
      short8 af = *(const short8*)((const char*)A_l + ((offA + ks) ^ swA));
      short8 b0 = *(const short8*)((const char*)B_l + ((offB0 + ks) ^ swB));
      short8 b1 = *(const short8*)((const char*)B_l + ((offB1 + ks) ^ swB));
      short8 b2 = *(const short8*)((const char*)B_l + ((offB2 + ks) ^ swB));
      short8 b3 = *(const short8*)((const char*)B_l + ((offB3 + ks) ^ swB));
      acc0 = __builtin_amdgcn_mfma_f32_16x16x32_bf16(af, b0, acc0, 0, 0, 0);
      acc1 = __builtin_amdgcn_mfma_f32_16x16x32_bf16(af, b1, acc1, 0, 0, 0);
      acc2 = __builtin_amdgcn_mfma_f32_16x16x32_bf16(af, b2, acc2, 0, 0, 0);
      acc3 = __builtin_amdgcn_mfma_f32_16x16x32_bf16(af, b3, acc3, 0, 0, 0);
    }
  }

  // --- epilogue: fp16 partials; D col=lane&15, row=lg*4+r (m89/m91) ---
  {
    __half* pb = partials +
        (((size_t)kp * 1024 + c * 256 + row0 + w * 16 + lg * 4) * 256) +
        col0 + lr;
#pragma unroll
    for (int r = 0; r < 4; ++r) {
      pb[r * 256 + 0]  = __float2half(acc0[r]);
      pb[r * 256 + 16] = __float2half(acc1[r]);
      pb[r * 256 + 32] = __float2half(acc2[r]);
      pb[r * 256 + 48] = __float2half(acc3[r]);
    }
  }
}

// grid = 256 blocks; thread = one pixel.
__global__ __launch_bounds__(256) void gs_finalize(
    const __half* __restrict__ partials, float* __restrict__ out) {
  int px = blockIdx.x * 256 + threadIdx.x;
  int row = px >> 8, col = px & 255;
  float s0 = 0.f, s1 = 0.f, s2 = 0.f, s3 = 0.f;
#pragma unroll
  for (int kp = 0; kp < KSPLIT; ++kp) {
    const __half* base = partials + (((size_t)kp * 4) * 256 + row) * 256 + col;
    s0 += __half2float(base[0 * 65536]);
    s1 += __half2float(base[1 * 65536]);
    s2 += __half2float(base[2 * 65536]);
    s3 += __half2float(base[3 * 65536]);
  }
  float inv = 1.0f / fmaxf(s3, 1e-5f);
  out[0 * PIX + px] = fminf(fmaxf(s0 * inv, 0.0f), 1.0f);
  out[1 * PIX + px] = fminf(fmaxf(s1 * inv, 0.0f), 1.0f);
  out[2 * PIX + px] = fminf(fmaxf(s2 * inv, 0.0f), 1.0f);
}

extern "C" void kernel_launch(void* const* d_in, const int* in_sizes, int n_in,
                              void* d_out, int out_size, void* d_ws, size_t ws_size,
                              hipStream_t stream) {
  const float* means = (const float*)d_in[0];
  // d_in[1] = quats (unused by reference)
  const float* scales = (const float*)d_in[2];
  const float* opac = (const float*)d_in[3];
  const float* colors = (const float*)d_in[4];
  float* out = (float*)d_out;

  // ws: partials [KSPLIT][1024][256] fp16 = 4 MB
  __half* partials = (__half*)d_ws;

  gs_mfma<<<dim3(16, 4, KSPLIT), 256, 0, stream>>>(
      means, scales, opac, colors, partials);
  gs_finalize<<<256, 256, 0, stream>>>(partials, out);
}

// Round 26
// 13.540 us; speedup vs baseline: 1.3505x; 1.0021x over previous
//
#include <hip/hip_runtime.h>
#include <hip/hip_fp16.h>

// GSplat renderer as a bf16 MFMA GEMM — R26 = R25 (13.57us) + two shaves:
//  (1) color folded into the recurrence seed (per-j A-mul gone),
//  (2) double-buffered LDS: stage(b0) / sync / [stage(b1) || MFMA(b0)] /
//      sync / MFMA(b1) — 2 barriers instead of 4, MFMA pipe hides under
//      staging VALU in the middle section (separate HW pipes, m114).
// Geometry: KSPLIT=8, KCH=128x2, grid (16,4,8)=512 blocks, LDS 69 KB
// (2 blocks/CU), fp16 partials (4 MB).

constexpr int PIX = 65536;
constexpr int KB = 256;      // gaussians per block (2 chunks of 128)
constexpr int KCH = 128;     // per staging chunk
constexpr int KSPLIT = 8;
constexpr int MT = 64;
constexpr int NT = 64;
constexpr float COORD_STEP = 2.0f / 255.0f;
constexpr float TWO_S = 2.0f * COORD_STEP;
constexpr float S_SQ = COORD_STEP * COORD_STEP;

typedef __attribute__((ext_vector_type(8))) short short8;
typedef __attribute__((ext_vector_type(4))) float f32x4;

__device__ __forceinline__ unsigned cvt_pk_bf16(float lo, float hi) {
  unsigned r;
  asm("v_cvt_pk_bf16_f32 %0, %1, %2" : "=v"(r) : "v"(lo), "v"(hi));
  return r;
}
__device__ __forceinline__ float ex2(float x) {
  return __builtin_amdgcn_exp2f(x);   // bare v_exp_f32
}
__device__ __forceinline__ float rcp_(float x) {
  return __builtin_amdgcn_rcpf(x);    // v_rcp_f32, 1 ulp
}
__device__ __forceinline__ float tanh_fast(float x) {
  float t = ex2(2.885390082f * x);    // e^{2x}
  return fmaf(-2.0f, rcp_(t + 1.0f), 1.0f);
}

__global__ __launch_bounds__(256) void gs_mfma(
    const float* __restrict__ means, const float* __restrict__ scales,
    const float* __restrict__ opac, const float* __restrict__ colors,
    __half* __restrict__ partials) {
  __shared__ unsigned short A_l[2][MT * KCH];  // 2 x 16 KB, swizzled
  __shared__ unsigned short B_l[2][NT * KCH];  // 2 x 16 KB, swizzled
  __shared__ float pxL[KB], pyL[KB], kKL[KB], colL[KB], qL[KB];  // 5 KB

  const int t = threadIdx.x;
  const int mt = blockIdx.x;          // 0..15: c = mt>>2, rowband (mt&3)*64
  const int nt = blockIdx.y;          // 0..3
  const int kp = blockIdx.z;          // 0..7
  const int c = mt >> 2;
  const int row0 = (mt & 3) * MT;
  const int col0 = nt * NT;

  // --- params for BOTH chunks (1 gaussian per thread, once) ---
  {
    int n = kp * KB + t;
    float mx = means[3 * n], my = means[3 * n + 1], mz = means[3 * n + 2];
    float scl = fmaxf((scales[3 * n] + scales[3 * n + 1] + scales[3 * n + 2]) * (1.0f / 3.0f), 1e-4f);
    float op = opac[n];
    float rzs = rcp_(fabsf(mz) + 1.0f);
    float sigma = fminf(fmaxf(scl * rzs, 0.02f), 0.5f);
    float inv_s = rcp_(sigma);
    float K = -0.72134752044f * inv_s * inv_s;  // -0.5/ln2 * inv_s^2
    pxL[t] = tanh_fast(mx * rzs);
    pyL[t] = tanh_fast(my * rzs);
    kKL[t] = K;
    qL[t] = ex2(2.0f * K * S_SQ);
    colL[t] = (c < 3) ? op * colors[3 * n + c] : op;
  }

  // MFMA lane mapping
  const int w = t >> 6;
  const int lr = t & 15;
  const int lg = (t >> 4) & 3;
  const int ra = w * 16 + lr;
  const unsigned offA = (unsigned)(ra * 256 + lg * 16);
  const unsigned swA = (unsigned)((ra & 7) << 4);
  const unsigned swB = (unsigned)((lr & 7) << 4);
  const unsigned offB0 = (unsigned)((0 * 16 + lr) * 256 + lg * 16);
  const unsigned offB1 = (unsigned)((1 * 16 + lr) * 256 + lg * 16);
  const unsigned offB2 = (unsigned)((2 * 16 + lr) * 256 + lg * 16);
  const unsigned offB3 = (unsigned)((3 * 16 + lr) * 256 + lg * 16);

  f32x4 acc0 = {0.f, 0.f, 0.f, 0.f};
  f32x4 acc1 = acc0, acc2 = acc0, acc3 = acc0;

  // staging thread mapping
  const int kq = (t & 31) << 2;       // 4 gaussians (local k)
  const int mq = (t >> 5) << 3;       // 8 rows/cols
  const int kbyte = (t & 31) << 3;

  // Staging: recurrence with color folded into the A seed.
  auto STAGE = [&](unsigned short* Ab, unsigned short* Bb, int cc) {
    const int kk = cc * KCH + kq;
    const float crA0 = -1.0f + COORD_STEP * (float)(row0 + mq);
    const float ccB0 = -1.0f + COORD_STEP * (float)(col0 + mq);
    float wA[4], rA[4], wB[4], rB[4], qv[4];
#pragma unroll
    for (int i = 0; i < 4; ++i) {
      float K = kKL[kk + i];
      float py = pyL[kk + i];
      float px = pxL[kk + i];
      qv[i] = qL[kk + i];
      float dA = crA0 - py;
      wA[i] = ex2(K * dA * dA) * colL[kk + i];   // color folded in
      rA[i] = ex2(K * fmaf(TWO_S, dA, S_SQ));
      float dB = ccB0 - px;
      wB[i] = ex2(K * dB * dB);
      rB[i] = ex2(K * fmaf(TWO_S, dB, S_SQ));
    }
#pragma unroll
    for (int j = 0; j < 8; ++j) {
      int m = mq + j;
      uint2 pa, pb;
      pa.x = cvt_pk_bf16(wA[0], wA[1]);
      pa.y = cvt_pk_bf16(wA[2], wA[3]);
      pb.x = cvt_pk_bf16(wB[0], wB[1]);
      pb.y = cvt_pk_bf16(wB[2], wB[3]);
      unsigned ds = (unsigned)((m * 256 + kbyte) ^ ((m & 7) << 4));
      *(uint2*)((char*)Ab + ds) = pa;
      *(uint2*)((char*)Bb + ds) = pb;
#pragma unroll
      for (int i = 0; i < 4; ++i) {
        wA[i] *= rA[i]; rA[i] *= qv[i];
        wB[i] *= rB[i]; rB[i] *= qv[i];
      }
    }
  };

  auto MFMA_PHASE = [&](const unsigned short* Ab, const unsigned short* Bb) {
#pragma unroll
    for (int s = 0; s < 4; ++s) {
      const unsigned ks = (unsigned)(s * 64);
      short8 af = *(const short8*)((const char*)Ab + ((offA + ks) ^ swA));
      short8 b0 = *(const short8*)((const char*)Bb + ((offB0 + ks) ^ swB));
      short8 b1 = *(const short8*)((const char*)Bb + ((offB1 + ks) ^ swB));
      short8 b2 = *(const short8*)((const char*)Bb + ((offB2 + ks) ^ swB));
      short8 b3 = *(const short8*)((const char*)Bb + ((offB3 + ks) ^ swB));
      acc0 = __builtin_amdgcn_mfma_f32_16x16x32_bf16(af, b0, acc0, 0, 0, 0);
      acc1 = __builtin_amdgcn_mfma_f32_16x16x32_bf16(af, b1, acc1, 0, 0, 0);
      acc2 = __builtin_amdgcn_mfma_f32_16x16x32_bf16(af, b2, acc2, 0, 0, 0);
      acc3 = __builtin_amdgcn_mfma_f32_16x16x32_bf16(af, b3, acc3, 0, 0, 0);
    }
  };

  __syncthreads();                 // params visible
  STAGE(A_l[0], B_l[0], 0);
  __syncthreads();                 // buf0 ready
  STAGE(A_l[1], B_l[1], 1);       // || MFMA(buf0): independent streams,
  MFMA_PHASE(A_l[0], B_l[0]);     // compiler interleaves across pipes
  __syncthreads();                 // buf1 ready
  MFMA_PHASE(A_l[1], B_l[1]);

  // --- epilogue: fp16 partials; D col=lane&15, row=lg*4+r (m89/m91) ---
  {
    __half* pb = partials +
        (((size_t)kp * 1024 + c * 256 + row0 + w * 16 + lg * 4) * 256) +
        col0 + lr;
#pragma unroll
    for (int r = 0; r < 4; ++r) {
      pb[r * 256 + 0]  = __float2half(acc0[r]);
      pb[r * 256 + 16] = __float2half(acc1[r]);
      pb[r * 256 + 32] = __float2half(acc2[r]);
      pb[r * 256 + 48] = __float2half(acc3[r]);
    }
  }
}

// grid = 256 blocks; thread = one pixel.
__global__ __launch_bounds__(256) void gs_finalize(
    const __half* __restrict__ partials, float* __restrict__ out) {
  int px = blockIdx.x * 256 + threadIdx.x;
  int row = px >> 8, col = px & 255;
  float s0 = 0.f, s1 = 0.f, s2 = 0.f, s3 = 0.f;
#pragma unroll
  for (int kp = 0; kp < KSPLIT; ++kp) {
    const __half* base = partials + (((size_t)kp * 4) * 256 + row) * 256 + col;
    s0 += __half2float(base[0 * 65536]);
    s1 += __half2float(base[1 * 65536]);
    s2 += __half2float(base[2 * 65536]);
    s3 += __half2float(base[3 * 65536]);
  }
  float inv = 1.0f / fmaxf(s3, 1e-5f);
  out[0 * PIX + px] = fminf(fmaxf(s0 * inv, 0.0f), 1.0f);
  out[1 * PIX + px] = fminf(fmaxf(s1 * inv, 0.0f), 1.0f);
  out[2 * PIX + px] = fminf(fmaxf(s2 * inv, 0.0f), 1.0f);
}

extern "C" void kernel_launch(void* const* d_in, const int* in_sizes, int n_in,
                              void* d_out, int out_size, void* d_ws, size_t ws_size,
                              hipStream_t stream) {
  const float* means = (const float*)d_in[0];
  // d_in[1] = quats (unused by reference)
  const float* scales = (const float*)d_in[2];
  const float* opac = (const float*)d_in[3];
  const float* colors = (const float*)d_in[4];
  float* out = (float*)d_out;

  // ws: partials [KSPLIT][1024][256] fp16 = 4 MB
  __half* partials = (__half*)d_ws;

  gs_mfma<<<dim3(16, 4, KSPLIT), 256, 0, stream>>>(
      means, scales, opac, colors, partials);
  gs_finalize<<<256, 256, 0, stream>>>(partials, out);
}